// Round 1
// baseline (2077.072 us; speedup 1.0000x reference)
//
#include <hip/hip_runtime.h>
#include <stdint.h>

typedef __attribute__((ext_vector_type(8))) short short8;
typedef __attribute__((ext_vector_type(4))) float f32x4;
typedef unsigned short u16;
typedef unsigned int u32;

#define NPER 6

// ws (bf16) element offsets
#define SW_OFF  0
#define TRW_OFF 131072
#define TW1_OFF 196608
#define CRW_OFF 262144
#define CW1_OFF 327680
#define TW2_OFF 393216
#define CW2_OFF 397312
#define CONV_N  401408

__device__ inline u16 f2b(float f){                 // f32 -> bf16 (RNE)
  u32 u = __builtin_bit_cast(u32, f);
  u = u + 0x7FFFu + ((u >> 16) & 1u);
  return (u16)(u >> 16);
}
__device__ inline float elu1(float x){ return x > 0.f ? x : (expf(x) - 1.f); }

__global__ __launch_bounds__(256) void convert_weights(
    const float* __restrict__ sw, const float* __restrict__ trw, const float* __restrict__ tw1,
    const float* __restrict__ crw, const float* __restrict__ cw1,
    const float* __restrict__ tw2, const float* __restrict__ cw2, u16* __restrict__ ws){
  int i = blockIdx.x * 256 + threadIdx.x;
  if (i >= CONV_N) return;
  float v;
  if (i < TRW_OFF) {
    v = sw[i];
  } else if (i < TW2_OFF) {
    int j = i - TRW_OFF; int m = j >> 16; int jj = j & 65535;
    const float* src = (m == 0) ? trw : (m == 1) ? tw1 : (m == 2) ? crw : cw1;
    v = src[jj];
  } else {
    int j = i - TW2_OFF;
    const float* src = (j < 4096) ? tw2 : cw2;
    int jj = j & 4095; int row = jj >> 8, col = jj & 255;
    v = (row < NPER) ? src[row * 256 + col] : 0.f;   // zero-pad rows 6..15
  }
  ws[i] = f2b(v);
}

// A-operand tile GEMM step: acc[2][4] covers rows wm*32 + {0..31}, cols wn*64 + {0..63}
template<int NK>
__device__ inline void gemm_from(const char* __restrict__ A, int rowBytes,
                                 const u16* __restrict__ W, int ldk, int kbaseW,
                                 f32x4 (&acc)[2][4], int wm, int wn, int lr, int lg){
  const int r0 = wm * 32 + lr;
  const int swz = (r0 & 7) << 4;            // same for r0 and r0+16
  #pragma unroll
  for (int ks = 0; ks < NK; ++ks){
    const int kA = (ks * 32 + lg * 8) * 2;  // byte offset in row
    short8 a0 = *(const short8*)(A + r0 * rowBytes + (kA ^ swz));
    short8 a1 = *(const short8*)(A + (r0 + 16) * rowBytes + (kA ^ swz));
    const int kW = kbaseW + ks * 32 + lg * 8;
    #pragma unroll
    for (int nf = 0; nf < 4; ++nf){
      short8 b = *(const short8*)(W + (size_t)((wn * 64 + nf * 16 + lr) * ldk + kW));
      acc[0][nf] = __builtin_amdgcn_mfma_f32_16x16x32_bf16(a0, b, acc[0][nf], 0, 0, 0);
      acc[1][nf] = __builtin_amdgcn_mfma_f32_16x16x32_bf16(a1, b, acc[1][nf], 0, 0, 0);
    }
  }
}

__global__ __launch_bounds__(512) void torsion_kernel(
    const float* __restrict__ h, const int* __restrict__ idxs,
    const float* __restrict__ sb,
    const float* __restrict__ t_rb, const float* __restrict__ t_b1, const float* __restrict__ t_b2,
    const float* __restrict__ c_rb, const float* __restrict__ c_b1, const float* __restrict__ c_b2,
    const u16* __restrict__ ws, float* __restrict__ out, int NT)
{
  __shared__ __attribute__((aligned(16))) char G[16384];    // gather chunk [64][128] bf16 / f32 partials [4][64][16]
  __shared__ __attribute__((aligned(16))) char Xb[32768];   // [64][256] bf16 (swizzled)
  __shared__ __attribute__((aligned(16))) char Yb[32768];
  __shared__ __attribute__((aligned(16))) char Vb[32768];
  __shared__ float SC[1024];                                // score [64][16] f32
  __shared__ float CO[1024];                                // coeff [64][16] f32

  const int tid = threadIdx.x;
  const int blk = blockIdx.x;
  const int lane = tid & 63;
  const int lr = lane & 15, lg = lane >> 4;
  const int w  = tid >> 6;
  const int wm = w & 1;        // row half   (rows wm*32 + 0..31)
  const int wn = w >> 1;       // col quarter (cols wn*64 + 0..63)

  f32x4 acc[2][4];
  #pragma unroll
  for (int i = 0; i < 2; ++i)
    #pragma unroll
    for (int j = 0; j < 4; ++j) acc[i][j] = (f32x4){0.f, 0.f, 0.f, 0.f};

  // ---------------- stage A: x = elu(concat(h[idx0..3]) @ sw.T + sb) ----------------
  #pragma unroll 1
  for (int p = 0; p < 4; ++p){
    __syncthreads();                       // all waves done reading previous chunk
    {
      const int row  = tid >> 3;           // 0..63
      const int part = tid & 7;            // 16 floats each
      const int grow = blk * 64 + row;
      const int nidx = (grow < NT) ? idxs[grow * 4 + p] : 0;
      const float4* src = (const float4*)(h + (size_t)nidx * 128 + part * 16);
      float4 q0 = src[0], q1 = src[1], q2 = src[2], q3 = src[3];
      short8 w0, w1;
      w0[0]=(short)f2b(q0.x); w0[1]=(short)f2b(q0.y); w0[2]=(short)f2b(q0.z); w0[3]=(short)f2b(q0.w);
      w0[4]=(short)f2b(q1.x); w0[5]=(short)f2b(q1.y); w0[6]=(short)f2b(q1.z); w0[7]=(short)f2b(q1.w);
      w1[0]=(short)f2b(q2.x); w1[1]=(short)f2b(q2.y); w1[2]=(short)f2b(q2.z); w1[3]=(short)f2b(q2.w);
      w1[4]=(short)f2b(q3.x); w1[5]=(short)f2b(q3.y); w1[6]=(short)f2b(q3.z); w1[7]=(short)f2b(q3.w);
      const int base = row * 256, swz = (row & 7) << 4;
      *(short8*)(G + base + ((part * 32) ^ swz))      = w0;
      *(short8*)(G + base + ((part * 32 + 16) ^ swz)) = w1;
    }
    __syncthreads();
    gemm_from<4>(G, 256, ws + SW_OFF, 512, p * 128, acc, wm, wn, lr, lg);
  }

  // finalize X: keep in regs (residual reuse) + write swizzled bf16 to Xb
  f32x4 xr[2][4];
  #pragma unroll
  for (int nf = 0; nf < 4; ++nf){
    const int col = wn * 64 + nf * 16 + lr;
    const float bias = sb[col];
    #pragma unroll
    for (int mf = 0; mf < 2; ++mf)
      #pragma unroll
      for (int r = 0; r < 4; ++r)
        xr[mf][nf][r] = elu1(acc[mf][nf][r] + bias);
  }
  #pragma unroll
  for (int mf = 0; mf < 2; ++mf)
    #pragma unroll
    for (int nf = 0; nf < 4; ++nf)
      #pragma unroll
      for (int r = 0; r < 4; ++r){
        const int row = wm * 32 + mf * 16 + lg * 4 + r;
        const int col = wn * 64 + nf * 16 + lr;
        *(u16*)(Xb + row * 512 + ((col * 2) ^ ((row & 7) << 4))) = f2b(xr[mf][nf][r]);
      }
  __syncthreads();

  float* Pf = (float*)G;

  // ---------------- two heads: c (score) then t (coeffs) ----------------
  #pragma unroll 1
  for (int head = 0; head < 2; ++head){
    const u16* RW = ws + (head == 0 ? CRW_OFF : TRW_OFF);
    const u16* W1 = ws + (head == 0 ? CW1_OFF : TW1_OFF);
    const u16* W2 = ws + (head == 0 ? CW2_OFF : TW2_OFF);
    const float* RB = head == 0 ? c_rb : t_rb;
    const float* B1 = head == 0 ? c_b1 : t_b1;
    const float* B2 = head == 0 ? c_b2 : t_b2;
    float* RED = head == 0 ? SC : CO;

    // residual: y = x + elu(x @ rw.T + rb)
    #pragma unroll
    for (int i = 0; i < 2; ++i)
      #pragma unroll
      for (int j = 0; j < 4; ++j) acc[i][j] = (f32x4){0.f, 0.f, 0.f, 0.f};
    gemm_from<8>(Xb, 512, RW, 256, 0, acc, wm, wn, lr, lg);
    #pragma unroll
    for (int nf = 0; nf < 4; ++nf){
      const int col = wn * 64 + nf * 16 + lr;
      const float bias = RB[col];
      #pragma unroll
      for (int mf = 0; mf < 2; ++mf)
        #pragma unroll
        for (int r = 0; r < 4; ++r){
          const float yv = xr[mf][nf][r] + elu1(acc[mf][nf][r] + bias);
          const int row = wm * 32 + mf * 16 + lg * 4 + r;
          *(u16*)(Yb + row * 512 + ((col * 2) ^ ((row & 7) << 4))) = f2b(yv);
        }
    }
    __syncthreads();

    // v = elu(y @ w1.T + b1)
    #pragma unroll
    for (int i = 0; i < 2; ++i)
      #pragma unroll
      for (int j = 0; j < 4; ++j) acc[i][j] = (f32x4){0.f, 0.f, 0.f, 0.f};
    gemm_from<8>(Yb, 512, W1, 256, 0, acc, wm, wn, lr, lg);
    #pragma unroll
    for (int nf = 0; nf < 4; ++nf){
      const int col = wn * 64 + nf * 16 + lr;
      const float bias = B1[col];
      #pragma unroll
      for (int mf = 0; mf < 2; ++mf)
        #pragma unroll
        for (int r = 0; r < 4; ++r){
          const float vv = elu1(acc[mf][nf][r] + bias);
          const int row = wm * 32 + mf * 16 + lg * 4 + r;
          *(u16*)(Vb + row * 512 + ((col * 2) ^ ((row & 7) << 4))) = f2b(vv);
        }
    }
    __syncthreads();

    // out = v @ w2p.T  (w2p zero-padded to [16][256]); K split across wn groups
    f32x4 a2[2];
    a2[0] = (f32x4){0.f, 0.f, 0.f, 0.f};
    a2[1] = (f32x4){0.f, 0.f, 0.f, 0.f};
    const int rr0 = wm * 32 + lr;
    const int vswz = (rr0 & 7) << 4;
    #pragma unroll
    for (int ks = 0; ks < 2; ++ks){
      const int k0 = wn * 64 + ks * 32;
      const int kb = (k0 + lg * 8) * 2;
      short8 a0 = *(const short8*)(Vb + rr0 * 512 + (kb ^ vswz));
      short8 a1 = *(const short8*)(Vb + (rr0 + 16) * 512 + (kb ^ vswz));
      short8 b  = *(const short8*)(W2 + (size_t)(lr * 256 + k0 + lg * 8));
      a2[0] = __builtin_amdgcn_mfma_f32_16x16x32_bf16(a0, b, a2[0], 0, 0, 0);
      a2[1] = __builtin_amdgcn_mfma_f32_16x16x32_bf16(a1, b, a2[1], 0, 0, 0);
    }
    #pragma unroll
    for (int mf = 0; mf < 2; ++mf)
      #pragma unroll
      for (int r = 0; r < 4; ++r){
        const int row = wm * 32 + mf * 16 + lg * 4 + r;
        Pf[wn * 1024 + row * 16 + lr] = a2[mf][r];
      }
    __syncthreads();
    for (int i = tid; i < 1024; i += 512){
      float s = Pf[i] + Pf[1024 + i] + Pf[2048 + i] + Pf[3072 + i];
      const int col = i & 15;
      if (col < NPER) s += B2[col];
      RED[i] = s;
    }
    __syncthreads();   // RED done; Pf reusable by next head
  }

  // ---------------- epilogue: score + k = coeffs * 1e-3 * sigmoid(score) ----------------
  if (tid < 384){
    const int row = tid / 6, col = tid - row * 6;
    const int grow = blk * 64 + row;
    if (grow < NT){
      const float s = SC[row * 16 + col];
      const float c = CO[row * 16 + col];
      out[(size_t)grow * 6 + col] = s;
      out[(size_t)NT * 6 + (size_t)grow * 6 + col] = c * 1e-3f * (1.0f / (1.0f + expf(-s)));
    }
  }
}

extern "C" void kernel_launch(void* const* d_in, const int* in_sizes, int n_in,
                              void* d_out, int out_size, void* d_ws, size_t ws_size,
                              hipStream_t stream){
  const float* h    = (const float*)d_in[0];
  const int*   idxs = (const int*)d_in[1];
  const float* sw   = (const float*)d_in[2];
  const float* sb   = (const float*)d_in[3];
  const float* trw  = (const float*)d_in[4];
  const float* trb  = (const float*)d_in[5];
  const float* tw1  = (const float*)d_in[6];
  const float* tb1  = (const float*)d_in[7];
  const float* tw2  = (const float*)d_in[8];
  const float* tb2  = (const float*)d_in[9];
  const float* crw  = (const float*)d_in[10];
  const float* crb  = (const float*)d_in[11];
  const float* cw1  = (const float*)d_in[12];
  const float* cb1  = (const float*)d_in[13];
  const float* cw2  = (const float*)d_in[14];
  const float* cb2  = (const float*)d_in[15];
  u16* ws  = (u16*)d_ws;
  float* out = (float*)d_out;
  const int NT = in_sizes[1] / 4;

  hipLaunchKernelGGL(convert_weights, dim3((CONV_N + 255) / 256), dim3(256), 0, stream,
                     sw, trw, tw1, crw, cw1, tw2, cw2, ws);
  const int nblk = (NT + 63) / 64;
  hipLaunchKernelGGL(torsion_kernel, dim3(nblk), dim3(512), 0, stream,
                     h, idxs, sb, trb, tb1, tb2, crb, cb1, cb2, ws, out, NT);
}

// Round 2
// 1228.476 us; speedup vs baseline: 1.6908x; 1.6908x over previous
//
#include <hip/hip_runtime.h>
#include <stdint.h>

typedef __attribute__((ext_vector_type(8))) short short8;
typedef __attribute__((ext_vector_type(4))) float f32x4;
typedef unsigned short u16;
typedef unsigned int u32;

#define NPER 6

// ws (bf16) element offsets
#define SW_OFF  0
#define TRW_OFF 131072
#define TW1_OFF 196608
#define CRW_OFF 262144
#define CW1_OFF 327680
#define TW2_OFF 393216
#define CW2_OFF 397312
#define CONV_N  401408

__device__ inline u16 f2b(float f){                 // f32 -> bf16 (RNE)
  u32 u = __builtin_bit_cast(u32, f);
  u = u + 0x7FFFu + ((u >> 16) & 1u);
  return (u16)(u >> 16);
}
__device__ inline float b2f(u16 v){
  u32 u = ((u32)v) << 16;
  return __builtin_bit_cast(float, u);
}
__device__ inline float elu1(float x){ return x > 0.f ? x : (__expf(x) - 1.f); }

__global__ __launch_bounds__(256) void convert_weights(
    const float* __restrict__ sw, const float* __restrict__ trw, const float* __restrict__ tw1,
    const float* __restrict__ crw, const float* __restrict__ cw1,
    const float* __restrict__ tw2, const float* __restrict__ cw2, u16* __restrict__ ws){
  int i = blockIdx.x * 256 + threadIdx.x;
  if (i >= CONV_N) return;
  float v;
  if (i < TRW_OFF) {
    v = sw[i];
  } else if (i < TW2_OFF) {
    int j = i - TRW_OFF; int m = j >> 16; int jj = j & 65535;
    const float* src = (m == 0) ? trw : (m == 1) ? tw1 : (m == 2) ? crw : cw1;
    v = src[jj];
  } else {
    int j = i - TW2_OFF;
    const float* src = (j < 4096) ? tw2 : cw2;
    int jj = j & 4095; int row = jj >> 8, col = jj & 255;
    v = (row < NPER) ? src[row * 256 + col] : 0.f;   // zero-pad rows 6..15
  }
  ws[i] = f2b(v);
}

// 64x32 wave-tile GEMM over K=256 from swizzled LDS (row stride 512B) vs bf16 weights [*][256]
__device__ inline void gemm256(const char* __restrict__ A, const u16* __restrict__ Wp,
                               f32x4 (&acc)[4][2], int w, int lr, int lg){
  #pragma unroll
  for (int ks = 0; ks < 8; ++ks){
    short8 a[4];
    #pragma unroll
    for (int mf = 0; mf < 4; ++mf){
      const int row = mf * 16 + lr;
      a[mf] = *(const short8*)(A + row * 512 + ((ks * 64 + lg * 16) ^ ((row & 7) << 4)));
    }
    const int kW = ks * 32 + lg * 8;
    #pragma unroll
    for (int nf = 0; nf < 2; ++nf){
      short8 b = *(const short8*)(Wp + (size_t)(w * 32 + nf * 16 + lr) * 256 + kW);
      #pragma unroll
      for (int mf = 0; mf < 4; ++mf)
        acc[mf][nf] = __builtin_amdgcn_mfma_f32_16x16x32_bf16(a[mf], b, acc[mf][nf], 0, 0, 0);
    }
  }
}

#define ZERO_ACC(acc) { _Pragma("unroll") for (int mf_ = 0; mf_ < 4; ++mf_){ \
  acc[mf_][0] = (f32x4){0.f,0.f,0.f,0.f}; acc[mf_][1] = (f32x4){0.f,0.f,0.f,0.f}; } }

__global__ __launch_bounds__(512, 4) void torsion_kernel(
    const float* __restrict__ h, const int* __restrict__ idxs,
    const float* __restrict__ sb,
    const float* __restrict__ t_rb, const float* __restrict__ t_b1, const float* __restrict__ t_b2,
    const float* __restrict__ c_rb, const float* __restrict__ c_b1, const float* __restrict__ c_b2,
    const u16* __restrict__ ws, float* __restrict__ out, int NT)
{
  // 16384 + 32768 + 32768 = 81920 B -> 2 blocks/CU
  __shared__ __attribute__((aligned(16))) char G[16384];    // gather dbuf 2x[64][64] bf16; later SC/CO
  __shared__ __attribute__((aligned(16))) char Xb[32768];   // [64][256] bf16 swizzled
  __shared__ __attribute__((aligned(16))) char Zb[32768];   // [64][256] bf16 swizzled (Y then V)

  const int tid = threadIdx.x, blk = blockIdx.x;
  const int lane = tid & 63, lr = lane & 15, lg = lane >> 4;
  const int w = tid >> 6;                    // 0..7: col group (cols w*32 .. w*32+31)

  // ---------------- gather setup: 8 chunks of K=64, double-buffered ----------------
  const int grow_row = tid >> 3;             // 0..63 (row this thread stages)
  const int gj = tid & 7;                    // 8 bf16 elements each
  const int gswz = (grow_row & 7) << 4;
  const int g_glob = blk * 64 + grow_row;
  int nidx4[4];
  #pragma unroll
  for (int s = 0; s < 4; ++s)
    nidx4[s] = (g_glob < NT) ? idxs[(size_t)g_glob * 4 + s] : 0;

  f32x4 acc[4][2];
  ZERO_ACC(acc);

  float4 q0, q1;
  {  // prologue: stage chunk 0
    const float* src = h + (size_t)nidx4[0] * 128 + gj * 8;
    q0 = ((const float4*)src)[0]; q1 = ((const float4*)src)[1];
    short8 v;
    v[0]=(short)f2b(q0.x); v[1]=(short)f2b(q0.y); v[2]=(short)f2b(q0.z); v[3]=(short)f2b(q0.w);
    v[4]=(short)f2b(q1.x); v[5]=(short)f2b(q1.y); v[6]=(short)f2b(q1.z); v[7]=(short)f2b(q1.w);
    *(short8*)(G + grow_row * 128 + ((gj * 16) ^ gswz)) = v;
  }
  __syncthreads();

  // ---------------- stage A: x = elu(concat(h[idx]) @ sw.T + sb), K=512 ----------------
  #pragma unroll
  for (int c = 0; c < 8; ++c){
    const char* cur = G + (c & 1) * 8192;
    char* nxt = G + ((c + 1) & 1) * 8192;
    if (c < 7){  // T14: issue next chunk's global loads early
      const float* src = h + (size_t)nidx4[(c + 1) >> 1] * 128 + ((c + 1) & 1) * 64 + gj * 8;
      q0 = ((const float4*)src)[0]; q1 = ((const float4*)src)[1];
    }
    #pragma unroll
    for (int ks = 0; ks < 2; ++ks){
      short8 a[4];
      #pragma unroll
      for (int mf = 0; mf < 4; ++mf){
        const int row = mf * 16 + lr;
        a[mf] = *(const short8*)(cur + row * 128 + ((ks * 64 + lg * 16) ^ ((row & 7) << 4)));
      }
      const int kW = c * 64 + ks * 32 + lg * 8;
      #pragma unroll
      for (int nf = 0; nf < 2; ++nf){
        short8 b = *(const short8*)(ws + SW_OFF + (size_t)(w * 32 + nf * 16 + lr) * 512 + kW);
        #pragma unroll
        for (int mf = 0; mf < 4; ++mf)
          acc[mf][nf] = __builtin_amdgcn_mfma_f32_16x16x32_bf16(a[mf], b, acc[mf][nf], 0, 0, 0);
      }
    }
    if (c < 7){  // write next chunk after compute (latency hidden under GEMM)
      short8 v;
      v[0]=(short)f2b(q0.x); v[1]=(short)f2b(q0.y); v[2]=(short)f2b(q0.z); v[3]=(short)f2b(q0.w);
      v[4]=(short)f2b(q1.x); v[5]=(short)f2b(q1.y); v[6]=(short)f2b(q1.z); v[7]=(short)f2b(q1.w);
      *(short8*)(nxt + grow_row * 128 + ((gj * 16) ^ gswz)) = v;
    }
    __syncthreads();
  }

  // finalize x: keep in regs (residual, reused by BOTH heads) + write swizzled bf16 Xb
  f32x4 xr[4][2];
  #pragma unroll
  for (int nf = 0; nf < 2; ++nf){
    const int col = w * 32 + nf * 16 + lr;
    const float bias = sb[col];
    #pragma unroll
    for (int mf = 0; mf < 4; ++mf)
      #pragma unroll
      for (int r = 0; r < 4; ++r){
        const float xv = elu1(acc[mf][nf][r] + bias);
        xr[mf][nf][r] = xv;
        const int row = mf * 16 + lg * 4 + r;
        *(u16*)(Xb + row * 512 + ((col * 2) ^ ((row & 7) << 4))) = f2b(xv);
      }
  }
  __syncthreads();

  float* SC = (float*)G;            // [64][8] f32 — gather region is dead now
  float* CO = (float*)(G + 2048);

  // ---------------- heads (sequential; share Zb via reg-staging) ----------------
  #pragma unroll 1
  for (int hd = 0; hd < 2; ++hd){
    const u16* RW = ws + (hd ? TRW_OFF : CRW_OFF);
    const u16* W1 = ws + (hd ? TW1_OFF : CW1_OFF);
    const u16* W2 = ws + (hd ? TW2_OFF : CW2_OFF);
    const float* RB = hd ? t_rb : c_rb;
    const float* B1 = hd ? t_b1 : c_b1;
    const float* B2 = hd ? t_b2 : c_b2;

    // y = x + elu(x @ rw.T + rb)
    ZERO_ACC(acc);
    gemm256((const char*)Xb, RW, acc, w, lr, lg);
    #pragma unroll
    for (int nf = 0; nf < 2; ++nf){
      const int col = w * 32 + nf * 16 + lr;
      const float bias = RB[col];
      #pragma unroll
      for (int mf = 0; mf < 4; ++mf)
        #pragma unroll
        for (int r = 0; r < 4; ++r){
          const int row = mf * 16 + lg * 4 + r;
          const float yv = xr[mf][nf][r] + elu1(acc[mf][nf][r] + bias);
          *(u16*)(Zb + row * 512 + ((col * 2) ^ ((row & 7) << 4))) = f2b(yv);
        }
    }
    __syncthreads();

    // v = elu(y @ w1.T + b1): compute to regs, then overwrite Zb
    ZERO_ACC(acc);
    gemm256((const char*)Zb, W1, acc, w, lr, lg);
    __syncthreads();                 // all Zb(Y) reads done
    #pragma unroll
    for (int nf = 0; nf < 2; ++nf){
      const int col = w * 32 + nf * 16 + lr;
      const float bias = B1[col];
      #pragma unroll
      for (int mf = 0; mf < 4; ++mf)
        #pragma unroll
        for (int r = 0; r < 4; ++r){
          const int row = mf * 16 + lg * 4 + r;
          *(u16*)(Zb + row * 512 + ((col * 2) ^ ((row & 7) << 4))) = f2b(elu1(acc[mf][nf][r] + bias));
        }
    }
    __syncthreads();

    // out16 = v @ w2p.T (w2p zero-padded [16][256]); waves 0..3 each take 16 rows, full K
    if (w < 4){
      f32x4 a2 = (f32x4){0.f, 0.f, 0.f, 0.f};
      const int r2 = w * 16 + lr;
      const int s2 = (r2 & 7) << 4;
      #pragma unroll
      for (int ks = 0; ks < 8; ++ks){
        short8 a = *(const short8*)(Zb + r2 * 512 + ((ks * 64 + lg * 16) ^ s2));
        short8 b = *(const short8*)(W2 + (size_t)lr * 256 + ks * 32 + lg * 8);
        a2 = __builtin_amdgcn_mfma_f32_16x16x32_bf16(a, b, a2, 0, 0, 0);
      }
      if (lr < 8){
        float* R = hd ? CO : SC;
        #pragma unroll
        for (int r = 0; r < 4; ++r){
          const int ro = w * 16 + lg * 4 + r;
          R[ro * 8 + lr] = a2[r] + (lr < NPER ? B2[lr] : 0.f);
        }
      }
    }
    __syncthreads();
  }

  // ---------------- epilogue ----------------
  if (tid < 384){
    const int row = tid / 6, col = tid - row * 6;
    const int grow = blk * 64 + row;
    if (grow < NT){
      const float s = SC[row * 8 + col];
      const float c0 = CO[row * 8 + col];
      out[(size_t)grow * 6 + col] = s;
      out[(size_t)NT * 6 + (size_t)grow * 6 + col] = c0 * 1e-3f * (1.f / (1.f + __expf(-s)));
    }
  }
}

extern "C" void kernel_launch(void* const* d_in, const int* in_sizes, int n_in,
                              void* d_out, int out_size, void* d_ws, size_t ws_size,
                              hipStream_t stream){
  const float* h    = (const float*)d_in[0];
  const int*   idxs = (const int*)d_in[1];
  const float* sw   = (const float*)d_in[2];
  const float* sb   = (const float*)d_in[3];
  const float* trw  = (const float*)d_in[4];
  const float* trb  = (const float*)d_in[5];
  const float* tw1  = (const float*)d_in[6];
  const float* tb1  = (const float*)d_in[7];
  const float* tw2  = (const float*)d_in[8];
  const float* tb2  = (const float*)d_in[9];
  const float* crw  = (const float*)d_in[10];
  const float* crb  = (const float*)d_in[11];
  const float* cw1  = (const float*)d_in[12];
  const float* cb1  = (const float*)d_in[13];
  const float* cw2  = (const float*)d_in[14];
  const float* cb2  = (const float*)d_in[15];
  u16* ws   = (u16*)d_ws;
  float* out = (float*)d_out;
  const int NT = in_sizes[1] / 4;

  hipLaunchKernelGGL(convert_weights, dim3((CONV_N + 255) / 256), dim3(256), 0, stream,
                     sw, trw, tw1, crw, cw1, tw2, cw2, ws);
  const int nblk = (NT + 63) / 64;
  hipLaunchKernelGGL(torsion_kernel, dim3(nblk), dim3(512), 0, stream,
                     h, idxs, sb, trb, tb1, tb2, crb, cb1, cb2, ws, out, NT);
}